// Round 1
// 308.906 us; speedup vs baseline: 1.0009x; 1.0009x over previous
//
#include <hip/hip_runtime.h>
#include <math.h>

#define NH 4
#define DIM 512
#define VDIM 512
#define QDIM 1024
#define KS 100
#define KN 100
#define TEMPERATURE 0.5f
#define BS 8
#define TS 2048
#define NHD (NH * DIM)          // 2048

// workspace layout (floats)
#define WS_QUERY   0                      // 16384
#define WS_QTAB    16384                  // 202*512 = 103424
#define WS_ENERGYP 119808                 // 4*32*2048 = 262144 (partial planes)
#define WS_CTX     381952                 // 16384
#define WS_P       398336                 // 202*100 = 20200
#define WS_F32_END 418536                 // *4 bytes (16B aligned)
// bf16 region: enc_bf [8388608 el], wk_bf [1048576], wv_bf [1048576]

typedef __bf16 bf16x8 __attribute__((ext_vector_type(8)));
typedef __bf16 bf16x4 __attribute__((ext_vector_type(4)));
typedef float  f32x4  __attribute__((ext_vector_type(4)));

#define AS1(p) ((const __attribute__((address_space(1))) void*)(p))
#define AS3(p) ((__attribute__((address_space(3))) void*)(p))

// tanh(x) = 1 - 2/(e^{2x}+1). Clamp-free: exp->inf => rcp->0 => 1;
// exp->0 => 1-2 = -1. 5 VALU inst (mul, exp, add, rcp, fma) vs 8 before.
__device__ __forceinline__ float fast_tanh(float x) {
    float e = __expf(2.0f * x);
    return 1.0f - __fdividef(2.0f, e + 1.0f);
}

// ---------------------------------------------------------------------------
// k_pre: one dispatch, 3 independent jobs:
//   [0, NCVT)      fp32->bf16 cvt of enc/Wk/Wv
//   [NCVT, +NQ2)   query GEMV: one WAVE per output o, loops all 8 batches
//   [NCVT+NQ2]     conv prefix (LDS-staged)
// ---------------------------------------------------------------------------
#define NE4 (BS * TS * VDIM / 4)      // 2097152
#define NW4 (NHD * VDIM / 4)          // 262144
#define NCVT ((NE4 + 2 * NW4) / 256)  // 10240
#define NQ2  (NHD / 4)                // 512 query blocks (4 waves each)
__global__ void k_pre(const float* __restrict__ enc, const float* __restrict__ Wk,
                      const float* __restrict__ Wv, __bf16* __restrict__ enc_bf,
                      __bf16* __restrict__ wk_bf, __bf16* __restrict__ wv_bf,
                      const float* __restrict__ dec, const float* __restrict__ Wq,
                      const float* __restrict__ bq, float* __restrict__ query,
                      const float* __restrict__ convw, float* __restrict__ P) {
    const int bx = blockIdx.x;
    if (bx < NCVT) {
        int i = bx * blockDim.x + threadIdx.x;
        const float* src; __bf16* dst; int k;
        if (i < NE4)            { src = enc; dst = enc_bf; k = i; }
        else if (i < NE4 + NW4) { src = Wk;  dst = wk_bf;  k = i - NE4; }
        else                    { src = Wv;  dst = wv_bf;  k = i - NE4 - NW4; }
        float4 v = ((const float4*)src)[k];
        bf16x4 o;
        o[0] = (__bf16)v.x; o[1] = (__bf16)v.y; o[2] = (__bf16)v.z; o[3] = (__bf16)v.w;
        ((bf16x4*)dst)[k] = o;
    } else if (bx < NCVT + NQ2) {
        int o = (bx - NCVT) * 4 + (threadIdx.x >> 6);    // 0..2047
        int lane = threadIdx.x & 63;
        const float* wr = Wq + (size_t)o * QDIM;
        float s[BS];
        #pragma unroll
        for (int b = 0; b < BS; ++b) s[b] = 0.f;
        #pragma unroll
        for (int i = 0; i < QDIM / 64; ++i) {
            float wv = wr[lane + 64 * i];
            #pragma unroll
            for (int b = 0; b < BS; ++b)
                s[b] = fmaf(wv, dec[b * QDIM + lane + 64 * i], s[b]);
        }
        #pragma unroll
        for (int off = 32; off > 0; off >>= 1)
            #pragma unroll
            for (int b = 0; b < BS; ++b) s[b] += __shfl_down(s[b], off);
        if (lane == 0) {
            float bias = bq[o];
            #pragma unroll
            for (int b = 0; b < BS; ++b) query[b * NHD + o] = tanhf(s[b] + bias);
        }
    } else {
        // conv prefix: P[j][k] = sum_{dt<j} sum_h convw[k,h,dt]
        __shared__ float cs[KN * (2 * KS + 1)];    // 80.4 KB
        int tid = threadIdx.x;                     // 256
        for (int i = tid; i < KN * (2 * KS + 1); i += 256) {
            int k = i / (2 * KS + 1);
            int dt = i - k * (2 * KS + 1);
            const float* wr = convw + k * (NH * (2 * KS + 1)) + dt;
            cs[i] = wr[0] + wr[201] + wr[402] + wr[603];
        }
        __syncthreads();
        if (tid < KN) {
            float acc = 0.f;
            P[tid] = 0.f;
            const float* c = cs + tid * (2 * KS + 1);
            for (int dt = 0; dt < 2 * KS + 1; ++dt) {
                acc += c[dt];
                P[(dt + 1) * KN + tid] = acc;
            }
        }
    }
}

// ---------------------------------------------------------------------------
// Qtab[j,d] = sum_k projw[d,k] * P[j,k]; spare blocks zero the ctx accumulator
// ---------------------------------------------------------------------------
__global__ void k_qtab(const float* __restrict__ P, const float* __restrict__ projw,
                       float* __restrict__ Qtab, float* __restrict__ ctx) {
    int tid = threadIdx.x;    // 512
    if (blockIdx.x >= 2 * KS + 2) {
        int z = (blockIdx.x - (2 * KS + 2)) * 512 + tid;   // float4 idx, 4096 total
        ((float4*)ctx)[z] = make_float4(0.f, 0.f, 0.f, 0.f);
        return;
    }
    int j = blockIdx.x;       // 0..201
    __shared__ float Pc[KN];
    if (tid < KN) Pc[tid] = P[j * KN + tid];
    __syncthreads();
    const float* pr = projw + tid * KN;
    float s = 0.f;
    #pragma unroll 4
    for (int k = 0; k < KN; ++k) s = fmaf(pr[k], Pc[k], s);
    Qtab[j * DIM + tid] = s;
}

// ===========================================================================
// GEMM core: 128x128 tile, BK=32, 512 threads = 8 waves 2x4, wave tile 64x32.
// R9 change (T4, counted vmcnt): depth-2 prefetch over THREE LDS buffers
// (48 KB). Per K-step: s_waitcnt vmcnt(2) retires exactly this step's 2
// global_load_lds while next step's 2 stay in flight ACROSS the barrier —
// the compiler's __syncthreads() vmcnt(0)-drain exposed full HBM/L2 latency
// 16x per block (K=512 -> only 16 steps, nothing to amortize the drain).
// lgkmcnt(0) before each barrier closes the buffer-reuse hazard (stage kk+2
// overwrites the buffer all waves finished ds_reading at kk-1).
// XCD-pinned flat grid: bid = ((b*16 + t0b)*2 + nhi)*8 + nlo -> XCD = nlo
// holds a 256 KB B slice L2-resident.
// ===========================================================================
#define GEMM1(Bptr)                                                               \
    const int bid = blockIdx.x;                                                    \
    const int b   = bid >> 8;                                                      \
    const int t0  = ((bid >> 4) & 15) << 7;                                        \
    const int n0  = ((((bid >> 3) & 1) << 3) | (bid & 7)) << 7;                    \
    const int len = enc_len[b];                                                    \
    if (t0 >= len) return;                                                         \
    const int tid = threadIdx.x;                                                   \
    const int w = tid >> 6, lane = tid & 63;                                       \
    const int wy = w >> 2, wx = w & 3;                                             \
    const int col = lane & 15, quad = lane >> 4;                                   \
    __shared__ __bf16 Ash[3 * 4096];                                               \
    __shared__ __bf16 Bsh[3 * 4096];                                               \
    f32x4 acc[4][2];                                                               \
    _Pragma("unroll")                                                              \
    for (int i = 0; i < 4; ++i)                                                    \
        _Pragma("unroll")                                                          \
        for (int j = 0; j < 2; ++j) acc[i][j] = (f32x4)0.f;                        \
    const __bf16* Abase = enc_bf + ((size_t)b * TS + t0) * VDIM;                   \
    const int sm = tid >> 2;                                                       \
    const int sj = (tid & 3) ^ (sm & 3) ^ ((sm >> 2) & 3);                         \
    const __bf16* gpA = Abase + (size_t)sm * VDIM + sj * 8;                        \
    const __bf16* gpB = (Bptr) + ((size_t)n0 + sm) * VDIM + sj * 8;                \
    const int cfr = quad ^ (col & 3) ^ ((col >> 2) & 3);                           \
    const char* pA = (const char*)Ash + (((wy * 64 + col) * 4 + cfr) << 4);        \
    const char* pB = (const char*)Bsh + (((wx * 32 + col) * 4 + cfr) << 4);        \
    __builtin_amdgcn_global_load_lds(AS1(gpA), AS3(Ash + w * 512), 16, 0, 0);      \
    __builtin_amdgcn_global_load_lds(AS1(gpB), AS3(Bsh + w * 512), 16, 0, 0);      \
    gpA += 32; gpB += 32;                                                          \
    __builtin_amdgcn_global_load_lds(AS1(gpA), AS3(Ash + 4096 + w * 512), 16, 0, 0); \
    __builtin_amdgcn_global_load_lds(AS1(gpB), AS3(Bsh + 4096 + w * 512), 16, 0, 0); \
    gpA += 32; gpB += 32;                                                          \
    _Pragma("unroll")                                                              \
    for (int kk = 0; kk < 16; ++kk) {                                              \
        if (kk < 15)                                                               \
            asm volatile("s_waitcnt vmcnt(2) lgkmcnt(0)\n\ts_barrier" ::: "memory"); \
        else                                                                       \
            asm volatile("s_waitcnt vmcnt(0) lgkmcnt(0)\n\ts_barrier" ::: "memory"); \
        if (kk < 14) {                                                             \
            const int sb = ((kk + 2) % 3) * 4096;                                  \
            __builtin_amdgcn_global_load_lds(AS1(gpA), AS3(Ash + sb + w * 512), 16, 0, 0); \
            __builtin_amdgcn_global_load_lds(AS1(gpB), AS3(Bsh + sb + w * 512), 16, 0, 0); \
            gpA += 32; gpB += 32;                                                  \
        }                                                                          \
        const int bo = (kk % 3) * 8192;                                            \
        bf16x8 af[4], bfr[2];                                                      \
        _Pragma("unroll")                                                          \
        for (int i = 0; i < 4; ++i) af[i] = *(const bf16x8*)(pA + bo + i * 1024);  \
        _Pragma("unroll")                                                          \
        for (int j = 0; j < 2; ++j) bfr[j] = *(const bf16x8*)(pB + bo + j * 1024); \
        _Pragma("unroll")                                                          \
        for (int i = 0; i < 4; ++i)                                                \
            _Pragma("unroll")                                                      \
            for (int j = 0; j < 2; ++j)                                            \
                acc[i][j] = __builtin_amdgcn_mfma_f32_16x16x32_bf16(               \
                    af[i], bfr[j], acc[i][j], 0, 0, 0);                            \
    }                                                                              \
    __syncthreads();
// acc[i][j][r] = C[t0+wy*64+i*16+quad*4+r][n0+wx*32+j*16+col]

// ---------------------------------------------------------------------------
// Energy pass: C = enc @ Wk^T, epilogue writes PARTIAL plane p = (n0>>7)&3:
//   energyP[p][b,h,t] = sum_{n in tile} tanh(tanh(C+bk)+query+loc) * gen_w[d]
// ---------------------------------------------------------------------------
__global__ __launch_bounds__(512, 4) void k_energy(
    const __bf16* __restrict__ enc_bf, const __bf16* __restrict__ wk_bf,
    const float* __restrict__ bk, const float* __restrict__ gen_w,
    const int* __restrict__ enc_len, const float* __restrict__ query,
    const float* __restrict__ Qtab, float* __restrict__ energyP) {
    GEMM1(wk_bf)

    const int h = n0 >> 9;
    const float inv_len = 1.0f / (float)len;
    float qv[2], gw[2], bkv[2], lI[2];
    int dj[2];
    #pragma unroll
    for (int j = 0; j < 2; ++j) {
        int n = n0 + wx * 32 + j * 16 + col;
        dj[j] = n & (DIM - 1);
        qv[j] = query[b * NHD + n];
        gw[j] = gen_w[dj[j]];
        bkv[j] = bk[n];
        lI[j] = fast_tanh((Qtab[(2 * KS + 1) * DIM + dj[j]] - Qtab[dj[j]]) * inv_len);
    }
    float* red = (float*)Ash;   // [128][4]
    #pragma unroll
    for (int i = 0; i < 4; ++i) {
        #pragma unroll
        for (int r = 0; r < 4; ++r) {
            int tl = wy * 64 + i * 16 + quad * 4 + r;
            int t = t0 + tl;
            float l[2];
            if (t >= KS && t < len - KS) {           // interior: loc const in t
                #pragma unroll
                for (int j = 0; j < 2; ++j) l[j] = lI[j];
            } else {
                int lo = KS - t; if (lo < 0) lo = 0;
                int hi = KS - t + len - 1; if (hi > 2 * KS) hi = 2 * KS;
                bool has = (hi >= lo);
                #pragma unroll
                for (int j = 0; j < 2; ++j) {
                    float cv = has
                        ? (Qtab[(hi + 1) * DIM + dj[j]] - Qtab[lo * DIM + dj[j]]) * inv_len
                        : 0.f;
                    l[j] = fast_tanh(cv);
                }
            }
            float s = 0.f;
            #pragma unroll
            for (int j = 0; j < 2; ++j) {
                float key = fast_tanh(acc[i][j][r] + bkv[j]);
                float e = fast_tanh(key + qv[j] + l[j]);
                s = fmaf(e, gw[j], s);
            }
            s += __shfl_xor(s, 1); s += __shfl_xor(s, 2);
            s += __shfl_xor(s, 4); s += __shfl_xor(s, 8);
            if (col == 0) red[tl * 4 + wx] = s;
        }
    }
    __syncthreads();
    if (tid < 128) {
        float s = red[tid * 4] + red[tid * 4 + 1] + red[tid * 4 + 2] + red[tid * 4 + 3];
        energyP[(size_t)((n0 >> 7) & 3) * 65536 + (size_t)(b * NH + h) * TS + t0 + tid] = s;
    }
}

// ---------------------------------------------------------------------------
// ctx pass: C = enc @ Wv^T, epilogue: ctx[b,n] += sum_t attn * tanh(C + bv)
// ---------------------------------------------------------------------------
__global__ __launch_bounds__(512, 4) void k_ctxg(
    const __bf16* __restrict__ enc_bf, const __bf16* __restrict__ wv_bf,
    const float* __restrict__ bv, const float* __restrict__ attn,
    const int* __restrict__ enc_len, float* __restrict__ ctx) {
    GEMM1(wv_bf)

    const int h = n0 >> 9;
    float att[4][4];
    #pragma unroll
    for (int i = 0; i < 4; ++i)
        #pragma unroll
        for (int r = 0; r < 4; ++r)
            att[i][r] = attn[(size_t)(b * NH + h) * TS + t0 + wy * 64 + i * 16 + quad * 4 + r];
    float* red = (float*)Ash;   // [128][2]
    #pragma unroll
    for (int j = 0; j < 2; ++j) {
        int nl = wx * 32 + j * 16 + col;
        float bvn = bv[n0 + nl];
        float s = 0.f;
        #pragma unroll
        for (int i = 0; i < 4; ++i)
            #pragma unroll
            for (int r = 0; r < 4; ++r)
                s = fmaf(att[i][r], fast_tanh(acc[i][j][r] + bvn), s);
        s += __shfl_xor(s, 16); s += __shfl_xor(s, 32);
        if (quad == 0) red[nl * 2 + wy] = s;
    }
    __syncthreads();
    if (tid < 128) {
        float s = red[tid * 2] + red[tid * 2 + 1];
        atomicAdd(&ctx[(size_t)b * NHD + n0 + tid], s);
    }
}

// ---------------------------------------------------------------------------
// softmax over t (masked): sums the 4 energy partial planes, writes attn
// ---------------------------------------------------------------------------
__global__ void k_softmax(const float* __restrict__ energyP, const int* __restrict__ enc_len,
                          const float* __restrict__ gen_b, float* __restrict__ attn) {
    int bh = blockIdx.x;          // 32
    int b = bh >> 2;
    int len = enc_len[b];
    int tid = threadIdx.x;        // 512
    int w = tid >> 6, lane = tid & 63;
    const float gb = gen_b[0];
    const float* e0 = energyP + (size_t)bh * TS;
    float ev[4];
    float mx = -INFINITY;
    #pragma unroll
    for (int i = 0; i < 4; ++i) {
        int t = i * 512 + tid;
        float e = -INFINITY;
        if (t < len) {
            float s = e0[t] + e0[65536 + t] + e0[131072 + t] + e0[196608 + t];
            e = (s + gb) * (1.0f / TEMPERATURE);
        }
        ev[i] = e;
        mx = fmaxf(mx, e);
    }
    __shared__ float sred[8], ssum[8];
    #pragma unroll
    for (int off = 32; off > 0; off >>= 1) mx = fmaxf(mx, __shfl_xor(mx, off));
    if (lane == 0) sred[w] = mx;
    __syncthreads();
    #pragma unroll
    for (int k = 0; k < 8; ++k) mx = fmaxf(mx, sred[k]);
    float ls = 0.f;
    #pragma unroll
    for (int i = 0; i < 4; ++i) {
        float ex = __expf(ev[i] - mx);
        ev[i] = ex;
        ls += ex;
    }
    #pragma unroll
    for (int off = 32; off > 0; off >>= 1) ls += __shfl_xor(ls, off);
    if (lane == 0) ssum[w] = ls;
    __syncthreads();
    float tot = 0.f;
    #pragma unroll
    for (int k = 0; k < 8; ++k) tot += ssum[k];
    float inv = 1.0f / tot;
    #pragma unroll
    for (int i = 0; i < 4; ++i)
        attn[(size_t)bh * TS + i * 512 + tid] = ev[i] * inv;
}

// ---------------------------------------------------------------------------
// context[b,o] = ctx[b,:] . merge_w[o,:] + merge_b[o]
// one WAVE per output o, loops all 8 batches -> merge_w read once (4 MB)
// ---------------------------------------------------------------------------
__global__ void k_merge(const float* __restrict__ ctx, const float* __restrict__ mw,
                        const float* __restrict__ mb, float* __restrict__ out) {
    int o = blockIdx.x * 4 + (threadIdx.x >> 6);   // 0..511
    int lane = threadIdx.x & 63;
    const float* wr = mw + (size_t)o * NHD;
    float s[BS];
    #pragma unroll
    for (int b = 0; b < BS; ++b) s[b] = 0.f;
    #pragma unroll
    for (int i = 0; i < NHD / 64; ++i) {
        float wv = wr[lane + 64 * i];
        #pragma unroll
        for (int b = 0; b < BS; ++b)
            s[b] = fmaf(wv, ctx[b * NHD + lane + 64 * i], s[b]);
    }
    #pragma unroll
    for (int off = 32; off > 0; off >>= 1)
        #pragma unroll
        for (int b = 0; b < BS; ++b) s[b] += __shfl_down(s[b], off);
    if (lane == 0) {
        float bias = mb[o];
        #pragma unroll
        for (int b = 0; b < BS; ++b) out[b * VDIM + o] = s[b] + bias;
    }
}

extern "C" void kernel_launch(void* const* d_in, const int* in_sizes, int n_in,
                              void* d_out, int out_size, void* d_ws, size_t ws_size,
                              hipStream_t stream) {
    const float* dec     = (const float*)d_in[0];
    const float* enc     = (const float*)d_in[1];
    const int*   enc_len = (const int*)d_in[2];
    const float* Wq      = (const float*)d_in[3];
    const float* bq      = (const float*)d_in[4];
    const float* Wk      = (const float*)d_in[5];
    const float* bk      = (const float*)d_in[6];
    const float* Wv      = (const float*)d_in[7];
    const float* bv      = (const float*)d_in[8];
    const float* convw   = (const float*)d_in[9];
    const float* projw   = (const float*)d_in[10];
    const float* gen_w   = (const float*)d_in[11];
    const float* gen_b   = (const float*)d_in[12];
    const float* merge_w = (const float*)d_in[13];
    const float* merge_b = (const float*)d_in[14];

    float* out    = (float*)d_out;               // attn [65536] ++ context [4096]
    float* ws     = (float*)d_ws;
    float* query  = ws + WS_QUERY;
    float* Qtab   = ws + WS_QTAB;
    float* energyP= ws + WS_ENERGYP;
    float* ctx    = ws + WS_CTX;
    float* Pws    = ws + WS_P;
    __bf16* enc_bf = (__bf16*)((char*)d_ws + (size_t)WS_F32_END * 4);
    __bf16* wk_bf  = enc_bf + (size_t)BS * TS * VDIM;
    __bf16* wv_bf  = wk_bf + (size_t)NHD * VDIM;

    k_pre<<<dim3(NCVT + NQ2 + 1), dim3(256), 0, stream>>>(
        enc, Wk, Wv, enc_bf, wk_bf, wv_bf, dec, Wq, bq, query, convw, Pws);
    k_qtab<<<dim3(2 * KS + 2 + 8), dim3(512), 0, stream>>>(Pws, projw, Qtab, ctx);
    k_energy<<<dim3(2048), dim3(512), 0, stream>>>(
        enc_bf, wk_bf, bk, gen_w, enc_len, query, Qtab, energyP);
    k_softmax<<<dim3(BS * NH), dim3(512), 0, stream>>>(energyP, enc_len, gen_b, out);
    k_ctxg<<<dim3(2048), dim3(512), 0, stream>>>(
        enc_bf, wv_bf, bv, out, enc_len, ctx);
    k_merge<<<dim3(VDIM / 4), dim3(256), 0, stream>>>(ctx, merge_w, merge_b, out + 65536);
}

// Round 2
// 287.309 us; speedup vs baseline: 1.0761x; 1.0752x over previous
//
#include <hip/hip_runtime.h>
#include <math.h>

#define NH 4
#define DIM 512
#define VDIM 512
#define QDIM 1024
#define KS 100
#define KN 100
#define TEMPERATURE 0.5f
#define BS 8
#define TS 2048
#define NHD (NH * DIM)          // 2048

// workspace layout (floats)
#define WS_QUERY   0                      // 16384
#define WS_QTAB    16384                  // 202*512 = 103424
#define WS_ENERGYP 119808                 // 4*32*2048 = 262144 (partial planes)
#define WS_CTX     381952                 // 16384
#define WS_P       398336                 // 202*100 = 20200
#define WS_F32_END 418536                 // *4 bytes (16B aligned)
// bf16 region: enc_bf [8388608 el], wk_bf [1048576], wv_bf [1048576]
// fp16 region: val [8*2048*2048] = 64 MiB  (value tensor, written by k_fused)

typedef __bf16 bf16x8 __attribute__((ext_vector_type(8)));
typedef __bf16 bf16x4 __attribute__((ext_vector_type(4)));
typedef _Float16 f16x8 __attribute__((ext_vector_type(8)));
typedef float  f32x4  __attribute__((ext_vector_type(4)));

#define AS1(p) ((const __attribute__((address_space(1))) void*)(p))
#define AS3(p) ((__attribute__((address_space(3))) void*)(p))

// tanh(x) = 1 - 2/(e^{2x}+1). Clamp-free: exp->inf => rcp->0 => 1;
// exp->0 => 1-2 = -1.
__device__ __forceinline__ float fast_tanh(float x) {
    float e = __expf(2.0f * x);
    return 1.0f - __fdividef(2.0f, e + 1.0f);
}

// ---------------------------------------------------------------------------
// k_pre: one dispatch, 3 independent jobs:
//   [0, NCVT)      fp32->bf16 cvt of enc/Wk/Wv
//   [NCVT, +NQ2)   query GEMV: one WAVE per output o, loops all 8 batches
//   [NCVT+NQ2]     conv prefix (LDS-staged)
// ---------------------------------------------------------------------------
#define NE4 (BS * TS * VDIM / 4)      // 2097152
#define NW4 (NHD * VDIM / 4)          // 262144
#define NCVT ((NE4 + 2 * NW4) / 256)  // 10240
#define NQ2  (NHD / 4)                // 512 query blocks (4 waves each)
__global__ void k_pre(const float* __restrict__ enc, const float* __restrict__ Wk,
                      const float* __restrict__ Wv, __bf16* __restrict__ enc_bf,
                      __bf16* __restrict__ wk_bf, __bf16* __restrict__ wv_bf,
                      const float* __restrict__ dec, const float* __restrict__ Wq,
                      const float* __restrict__ bq, float* __restrict__ query,
                      const float* __restrict__ convw, float* __restrict__ P) {
    const int bx = blockIdx.x;
    if (bx < NCVT) {
        int i = bx * blockDim.x + threadIdx.x;
        const float* src; __bf16* dst; int k;
        if (i < NE4)            { src = enc; dst = enc_bf; k = i; }
        else if (i < NE4 + NW4) { src = Wk;  dst = wk_bf;  k = i - NE4; }
        else                    { src = Wv;  dst = wv_bf;  k = i - NE4 - NW4; }
        float4 v = ((const float4*)src)[k];
        bf16x4 o;
        o[0] = (__bf16)v.x; o[1] = (__bf16)v.y; o[2] = (__bf16)v.z; o[3] = (__bf16)v.w;
        ((bf16x4*)dst)[k] = o;
    } else if (bx < NCVT + NQ2) {
        int o = (bx - NCVT) * 4 + (threadIdx.x >> 6);    // 0..2047
        int lane = threadIdx.x & 63;
        const float* wr = Wq + (size_t)o * QDIM;
        float s[BS];
        #pragma unroll
        for (int b = 0; b < BS; ++b) s[b] = 0.f;
        #pragma unroll
        for (int i = 0; i < QDIM / 64; ++i) {
            float wv = wr[lane + 64 * i];
            #pragma unroll
            for (int b = 0; b < BS; ++b)
                s[b] = fmaf(wv, dec[b * QDIM + lane + 64 * i], s[b]);
        }
        #pragma unroll
        for (int off = 32; off > 0; off >>= 1)
            #pragma unroll
            for (int b = 0; b < BS; ++b) s[b] += __shfl_down(s[b], off);
        if (lane == 0) {
            float bias = bq[o];
            #pragma unroll
            for (int b = 0; b < BS; ++b) query[b * NHD + o] = tanhf(s[b] + bias);
        }
    } else {
        // conv prefix: P[j][k] = sum_{dt<j} sum_h convw[k,h,dt]
        __shared__ float cs[KN * (2 * KS + 1)];    // 80.4 KB
        int tid = threadIdx.x;                     // 256
        for (int i = tid; i < KN * (2 * KS + 1); i += 256) {
            int k = i / (2 * KS + 1);
            int dt = i - k * (2 * KS + 1);
            const float* wr = convw + k * (NH * (2 * KS + 1)) + dt;
            cs[i] = wr[0] + wr[201] + wr[402] + wr[603];
        }
        __syncthreads();
        if (tid < KN) {
            float acc = 0.f;
            P[tid] = 0.f;
            const float* c = cs + tid * (2 * KS + 1);
            for (int dt = 0; dt < 2 * KS + 1; ++dt) {
                acc += c[dt];
                P[(dt + 1) * KN + tid] = acc;
            }
        }
    }
}

// ---------------------------------------------------------------------------
// Qtab[j,d] = sum_k projw[d,k] * P[j,k]; spare blocks zero the ctx accumulator
// ---------------------------------------------------------------------------
__global__ void k_qtab(const float* __restrict__ P, const float* __restrict__ projw,
                       float* __restrict__ Qtab, float* __restrict__ ctx) {
    int tid = threadIdx.x;    // 512
    if (blockIdx.x >= 2 * KS + 2) {
        int z = (blockIdx.x - (2 * KS + 2)) * 512 + tid;   // float4 idx, 4096 total
        ((float4*)ctx)[z] = make_float4(0.f, 0.f, 0.f, 0.f);
        return;
    }
    int j = blockIdx.x;       // 0..201
    __shared__ float Pc[KN];
    if (tid < KN) Pc[tid] = P[j * KN + tid];
    __syncthreads();
    const float* pr = projw + tid * KN;
    float s = 0.f;
    #pragma unroll 4
    for (int k = 0; k < KN; ++k) s = fmaf(pr[k], Pc[k], s);
    Qtab[j * DIM + tid] = s;
}

// ===========================================================================
// k_fused: ONE pass over enc computes BOTH GEMMs (enc@Wk^T and enc@Wv^T),
// sharing the A-tile loads that dominated the old two-dispatch traffic
// (~390 MB of global_load_lds per pass; A re-read by every n-block).
// 128x128 tile, BK=32, 512 threads = 8 waves 2x4, wave tile 64x32 per B.
// Per K-step: 4 A-frags shared, 2 Bk-frags -> 8 MFMA accE, 2 Bv-frags ->
// 8 MFMA accV (16 MFMA per step vs 8 before -> better compute:sync ratio).
// 3-buffer counted vmcnt(3) pipeline (depth-2); occupancy is VGPR-capped at
// 2 blocks/CU so 72 KB LDS is free (144 KB/CU).
// Epilogue: energy reduction (as before) + value = tanh(accV+bv) staged in
// LDS as fp16 [128t][128n], cooperatively stored coalesced to val[b][t][n].
// ===========================================================================
__global__ __launch_bounds__(512, 4) void k_fused(
    const __bf16* __restrict__ enc_bf, const __bf16* __restrict__ wk_bf,
    const __bf16* __restrict__ wv_bf, const float* __restrict__ bk,
    const float* __restrict__ bv, const float* __restrict__ gen_w,
    const int* __restrict__ enc_len, const float* __restrict__ query,
    const float* __restrict__ Qtab, float* __restrict__ energyP,
    _Float16* __restrict__ val) {
    const int bid = blockIdx.x;
    const int b   = bid >> 8;
    const int t0  = ((bid >> 4) & 15) << 7;
    const int n0  = ((((bid >> 3) & 1) << 3) | (bid & 7)) << 7;
    const int len = enc_len[b];
    if (t0 >= len) return;
    const int tid = threadIdx.x;
    const int w = tid >> 6, lane = tid & 63;
    const int wy = w >> 2, wx = w & 3;
    const int col = lane & 15, quad = lane >> 4;
    // smem: 3 buffers x (A 4096 | Bk 4096 | Bv 4096) bf16 = 72 KB
    __shared__ __bf16 smem[3 * 12288];
    f32x4 accE[4][2], accV[4][2];
    #pragma unroll
    for (int i = 0; i < 4; ++i)
        #pragma unroll
        for (int j = 0; j < 2; ++j) { accE[i][j] = (f32x4)0.f; accV[i][j] = (f32x4)0.f; }
    const int sm = tid >> 2;
    const int sj = (tid & 3) ^ (sm & 3) ^ ((sm >> 2) & 3);
    const __bf16* gpA  = enc_bf + ((size_t)b * TS + t0) * VDIM + (size_t)sm * VDIM + sj * 8;
    const __bf16* gpBk = wk_bf + ((size_t)n0 + sm) * VDIM + sj * 8;
    const __bf16* gpBv = wv_bf + ((size_t)n0 + sm) * VDIM + sj * 8;
    const int cfr = quad ^ (col & 3) ^ ((col >> 2) & 3);
    const char* pbase = (const char*)smem;
    const int offA = (((wy * 64 + col) * 4 + cfr) << 4);
    const int offB = (((wx * 32 + col) * 4 + cfr) << 4);
    // prologue: stage steps 0 and 1 (3 loads each -> 6 outstanding)
    #define STG(sbe)                                                               \
        __builtin_amdgcn_global_load_lds(AS1(gpA),  AS3(smem + (sbe) + w * 512), 16, 0, 0);        \
        __builtin_amdgcn_global_load_lds(AS1(gpBk), AS3(smem + (sbe) + 4096 + w * 512), 16, 0, 0); \
        __builtin_amdgcn_global_load_lds(AS1(gpBv), AS3(smem + (sbe) + 8192 + w * 512), 16, 0, 0); \
        gpA += 32; gpBk += 32; gpBv += 32;
    STG(0)
    STG(12288)
    #pragma unroll
    for (int kk = 0; kk < 16; ++kk) {
        if (kk < 15)
            asm volatile("s_waitcnt vmcnt(3) lgkmcnt(0)\n\ts_barrier" ::: "memory");
        else
            asm volatile("s_waitcnt vmcnt(0) lgkmcnt(0)\n\ts_barrier" ::: "memory");
        if (kk < 14) {
            const int sbe = ((kk + 2) % 3) * 12288;
            STG(sbe)
        }
        const int bo = (kk % 3) * 24576;   // bytes
        bf16x8 af[4], bfr[2];
        #pragma unroll
        for (int i = 0; i < 4; ++i) af[i] = *(const bf16x8*)(pbase + bo + offA + i * 1024);
        #pragma unroll
        for (int j = 0; j < 2; ++j) bfr[j] = *(const bf16x8*)(pbase + bo + 8192 + offB + j * 1024);
        #pragma unroll
        for (int i = 0; i < 4; ++i)
            #pragma unroll
            for (int j = 0; j < 2; ++j)
                accE[i][j] = __builtin_amdgcn_mfma_f32_16x16x32_bf16(af[i], bfr[j], accE[i][j], 0, 0, 0);
        #pragma unroll
        for (int j = 0; j < 2; ++j) bfr[j] = *(const bf16x8*)(pbase + bo + 16384 + offB + j * 1024);
        #pragma unroll
        for (int i = 0; i < 4; ++i)
            #pragma unroll
            for (int j = 0; j < 2; ++j)
                accV[i][j] = __builtin_amdgcn_mfma_f32_16x16x32_bf16(af[i], bfr[j], accV[i][j], 0, 0, 0);
    }
    #undef STG
    __syncthreads();
    // acc?[i][j][r] = C[t0+wy*64+i*16+quad*4+r][n0+wx*32+j*16+col]

    // ---- epilogue smem carve: stage fp16 [128][128] = 32 KB @0, red @32 KB
    _Float16* stage = (_Float16*)smem;
    float* red = (float*)((char*)smem + 32768);   // [128][4]

    // ---- energy reduction (unchanged math) ----
    const int h = n0 >> 9;
    const float inv_len = 1.0f / (float)len;
    float qv[2], gw[2], bkv[2], bvv[2], lI[2];
    int dj[2];
    #pragma unroll
    for (int j = 0; j < 2; ++j) {
        int n = n0 + wx * 32 + j * 16 + col;
        dj[j] = n & (DIM - 1);
        qv[j] = query[b * NHD + n];
        gw[j] = gen_w[dj[j]];
        bkv[j] = bk[n];
        bvv[j] = bv[n];
        lI[j] = fast_tanh((Qtab[(2 * KS + 1) * DIM + dj[j]] - Qtab[dj[j]]) * inv_len);
    }
    #pragma unroll
    for (int i = 0; i < 4; ++i) {
        #pragma unroll
        for (int r = 0; r < 4; ++r) {
            int tl = wy * 64 + i * 16 + quad * 4 + r;
            int t = t0 + tl;
            float l[2];
            if (t >= KS && t < len - KS) {           // interior: loc const in t
                #pragma unroll
                for (int j = 0; j < 2; ++j) l[j] = lI[j];
            } else {
                int lo = KS - t; if (lo < 0) lo = 0;
                int hi = KS - t + len - 1; if (hi > 2 * KS) hi = 2 * KS;
                bool has = (hi >= lo);
                #pragma unroll
                for (int j = 0; j < 2; ++j) {
                    float cv = has
                        ? (Qtab[(hi + 1) * DIM + dj[j]] - Qtab[lo * DIM + dj[j]]) * inv_len
                        : 0.f;
                    l[j] = fast_tanh(cv);
                }
            }
            float s = 0.f;
            #pragma unroll
            for (int j = 0; j < 2; ++j) {
                float key = fast_tanh(accE[i][j][r] + bkv[j]);
                float e = fast_tanh(key + qv[j] + l[j]);
                s = fmaf(e, gw[j], s);
            }
            s += __shfl_xor(s, 1); s += __shfl_xor(s, 2);
            s += __shfl_xor(s, 4); s += __shfl_xor(s, 8);
            if (col == 0) red[tl * 4 + wx] = s;
        }
    }
    // ---- value: tanh(accV+bv) -> fp16 stage[tl][nl] ----
    #pragma unroll
    for (int j = 0; j < 2; ++j) {
        #pragma unroll
        for (int i = 0; i < 4; ++i)
            #pragma unroll
            for (int r = 0; r < 4; ++r) {
                int tl = wy * 64 + i * 16 + quad * 4 + r;
                stage[tl * 128 + wx * 32 + j * 16 + col] =
                    (_Float16)fast_tanh(accV[i][j][r] + bvv[j]);
            }
    }
    __syncthreads();
    if (tid < 128) {
        float s = red[tid * 4] + red[tid * 4 + 1] + red[tid * 4 + 2] + red[tid * 4 + 3];
        energyP[(size_t)((n0 >> 7) & 3) * 65536 + (size_t)(b * NH + h) * TS + t0 + tid] = s;
    }
    // cooperative coalesced store of the 32 KB value tile (rows of 256B)
    #pragma unroll
    for (int it = 0; it < 4; ++it) {
        int idx = it * 512 + tid;        // 16B chunk id, 0..2047
        int row = idx >> 4, seg = idx & 15;
        *(float4*)((char*)(val + ((size_t)b * TS + t0 + row) * NHD + n0) + seg * 16) =
            ((const float4*)stage)[idx];
    }
}

// ---------------------------------------------------------------------------
// softmax over t (masked): sums the 4 energy partial planes, writes attn
// ---------------------------------------------------------------------------
__global__ void k_softmax(const float* __restrict__ energyP, const int* __restrict__ enc_len,
                          const float* __restrict__ gen_b, float* __restrict__ attn) {
    int bh = blockIdx.x;          // 32
    int b = bh >> 2;
    int len = enc_len[b];
    int tid = threadIdx.x;        // 512
    int w = tid >> 6, lane = tid & 63;
    const float gb = gen_b[0];
    const float* e0 = energyP + (size_t)bh * TS;
    float ev[4];
    float mx = -INFINITY;
    #pragma unroll
    for (int i = 0; i < 4; ++i) {
        int t = i * 512 + tid;
        float e = -INFINITY;
        if (t < len) {
            float s = e0[t] + e0[65536 + t] + e0[131072 + t] + e0[196608 + t];
            e = (s + gb) * (1.0f / TEMPERATURE);
        }
        ev[i] = e;
        mx = fmaxf(mx, e);
    }
    __shared__ float sred[8], ssum[8];
    #pragma unroll
    for (int off = 32; off > 0; off >>= 1) mx = fmaxf(mx, __shfl_xor(mx, off));
    if (lane == 0) sred[w] = mx;
    __syncthreads();
    #pragma unroll
    for (int k = 0; k < 8; ++k) mx = fmaxf(mx, sred[k]);
    float ls = 0.f;
    #pragma unroll
    for (int i = 0; i < 4; ++i) {
        float ex = __expf(ev[i] - mx);
        ev[i] = ex;
        ls += ex;
    }
    #pragma unroll
    for (int off = 32; off > 0; off >>= 1) ls += __shfl_xor(ls, off);
    if (lane == 0) ssum[w] = ls;
    __syncthreads();
    float tot = 0.f;
    #pragma unroll
    for (int k = 0; k < 8; ++k) tot += ssum[k];
    float inv = 1.0f / tot;
    #pragma unroll
    for (int i = 0; i < 4; ++i)
        attn[(size_t)bh * TS + i * 512 + tid] = ev[i] * inv;
}

// ---------------------------------------------------------------------------
// k_ctx2: ctx[b,n] += sum_t attn[b,h,t] * val[b,t,n]  (memory-bound sweep of
// the fp16 value tensor; replaces the second full GEMM pass).
// grid: 8b x 16 n-chunks(128) x 8 t-slices(256); 256 threads.
// thread: 8 consecutive n (16B fp16 load), 16 t-rows strided.
// ---------------------------------------------------------------------------
__global__ __launch_bounds__(256) void k_ctx2(const _Float16* __restrict__ val,
                                              const float* __restrict__ attn,
                                              const int* __restrict__ enc_len,
                                              float* __restrict__ ctx) {
    const int blk = blockIdx.x;
    const int b   = blk >> 7;
    const int nc  = (blk >> 3) & 15;
    const int tsl = blk & 7;
    const int len = enc_len[b];
    const int t0  = tsl * 256;
    if (t0 >= len) return;
    const int n0 = nc * 128;
    const int h  = n0 >> 9;
    const int tid = threadIdx.x;
    const int tn = tid & 15, tr = tid >> 4;
    const float* ar = attn + (size_t)(b * NH + h) * TS;
    float acc[8];
    #pragma unroll
    for (int k = 0; k < 8; ++k) acc[k] = 0.f;
    int tend = t0 + 256; if (tend > len) tend = len;
    for (int t = t0 + tr; t < tend; t += 16) {
        float a = ar[t];
        f16x8 v = *(const f16x8*)(val + ((size_t)b * TS + t) * NHD + n0 + tn * 8);
        #pragma unroll
        for (int k = 0; k < 8; ++k) acc[k] = fmaf(a, (float)v[k], acc[k]);
    }
    __shared__ float cred[16][128];
    #pragma unroll
    for (int k = 0; k < 8; ++k) cred[tr][tn * 8 + k] = acc[k];
    __syncthreads();
    if (tid < 128) {
        float s = 0.f;
        #pragma unroll
        for (int r = 0; r < 16; ++r) s += cred[r][tid];
        atomicAdd(&ctx[(size_t)b * NHD + n0 + tid], s);
    }
}

// ---------------------------------------------------------------------------
// context[b,o] = ctx[b,:] . merge_w[o,:] + merge_b[o]
// one WAVE per output o, loops all 8 batches -> merge_w read once (4 MB)
// ---------------------------------------------------------------------------
__global__ void k_merge(const float* __restrict__ ctx, const float* __restrict__ mw,
                        const float* __restrict__ mb, float* __restrict__ out) {
    int o = blockIdx.x * 4 + (threadIdx.x >> 6);   // 0..511
    int lane = threadIdx.x & 63;
    const float* wr = mw + (size_t)o * NHD;
    float s[BS];
    #pragma unroll
    for (int b = 0; b < BS; ++b) s[b] = 0.f;
    #pragma unroll
    for (int i = 0; i < NHD / 64; ++i) {
        float wv = wr[lane + 64 * i];
        #pragma unroll
        for (int b = 0; b < BS; ++b)
            s[b] = fmaf(wv, ctx[b * NHD + lane + 64 * i], s[b]);
    }
    #pragma unroll
    for (int off = 32; off > 0; off >>= 1)
        #pragma unroll
        for (int b = 0; b < BS; ++b) s[b] += __shfl_down(s[b], off);
    if (lane == 0) {
        float bias = mb[o];
        #pragma unroll
        for (int b = 0; b < BS; ++b) out[b * VDIM + o] = s[b] + bias;
    }
}

extern "C" void kernel_launch(void* const* d_in, const int* in_sizes, int n_in,
                              void* d_out, int out_size, void* d_ws, size_t ws_size,
                              hipStream_t stream) {
    const float* dec     = (const float*)d_in[0];
    const float* enc     = (const float*)d_in[1];
    const int*   enc_len = (const int*)d_in[2];
    const float* Wq      = (const float*)d_in[3];
    const float* bq      = (const float*)d_in[4];
    const float* Wk      = (const float*)d_in[5];
    const float* bk      = (const float*)d_in[6];
    const float* Wv      = (const float*)d_in[7];
    const float* bv      = (const float*)d_in[8];
    const float* convw   = (const float*)d_in[9];
    const float* projw   = (const float*)d_in[10];
    const float* gen_w   = (const float*)d_in[11];
    const float* gen_b   = (const float*)d_in[12];
    const float* merge_w = (const float*)d_in[13];
    const float* merge_b = (const float*)d_in[14];

    float* out    = (float*)d_out;               // attn [65536] ++ context [4096]
    float* ws     = (float*)d_ws;
    float* query  = ws + WS_QUERY;
    float* Qtab   = ws + WS_QTAB;
    float* energyP= ws + WS_ENERGYP;
    float* ctx    = ws + WS_CTX;
    float* Pws    = ws + WS_P;
    __bf16* enc_bf = (__bf16*)((char*)d_ws + (size_t)WS_F32_END * 4);
    __bf16* wk_bf  = enc_bf + (size_t)BS * TS * VDIM;
    __bf16* wv_bf  = wk_bf + (size_t)NHD * VDIM;
    _Float16* val  = (_Float16*)(wv_bf + (size_t)NHD * VDIM);   // 64 MiB

    k_pre<<<dim3(NCVT + NQ2 + 1), dim3(256), 0, stream>>>(
        enc, Wk, Wv, enc_bf, wk_bf, wv_bf, dec, Wq, bq, query, convw, Pws);
    k_qtab<<<dim3(2 * KS + 2 + 8), dim3(512), 0, stream>>>(Pws, projw, Qtab, ctx);
    k_fused<<<dim3(2048), dim3(512), 0, stream>>>(
        enc_bf, wk_bf, wv_bf, bk, bv, gen_w, enc_len, query, Qtab, energyP, val);
    k_softmax<<<dim3(BS * NH), dim3(512), 0, stream>>>(energyP, enc_len, gen_b, out);
    k_ctx2<<<dim3(BS * 16 * 8), dim3(256), 0, stream>>>(val, out, enc_len, ctx);
    k_merge<<<dim3(VDIM / 4), dim3(256), 0, stream>>>(ctx, merge_w, merge_b, out + 65536);
}